// Round 10
// baseline (456.950 us; speedup 1.0000x reference)
//
#include <hip/hip_runtime.h>
#include <hip/hip_cooperative_groups.h>
#include <math.h>

namespace cg = cooperative_groups;

// Problem constants: x [4, 256, 64, 64] fp32
#define BB   4
#define CC   256
#define NN   4096      // 64*64 spatial
#define GG   8
#define CPG  32        // channels per group
#define EPSV 1e-5f
#define SCALE 0.0625f  // 1/sqrt(256)
#define NSPLIT 4
#define PSTR 40        // ldsP row stride in ushorts (80 B: 16B-aligned rows)
#define SMEM_BYTES 75776

typedef __attribute__((ext_vector_type(8))) short bf16x8;  // 8 bf16 = 4 VGPRs
typedef __attribute__((ext_vector_type(4))) float f32x4;

struct alignas(8) us4 { unsigned short x, y, z, w; };

static __device__ __forceinline__ unsigned short f2bf(float f) {
    union { float f; unsigned int u; } a; a.f = f;
    unsigned int r = a.u + 0x7fffu + ((a.u >> 16) & 1u);   // RNE
    return (unsigned short)(r >> 16);
}
// async global->LDS, 16B/lane: per-lane gptr, wave-uniform LDS base (+lane*16 by HW)
static __device__ __forceinline__ void async16(const unsigned short* g, unsigned short* l) {
    __builtin_amdgcn_global_load_lds(
        (const __attribute__((address_space(1))) unsigned int*)g,
        (__attribute__((address_space(3))) unsigned int*)l,
        16, 0, 0);
}

// Chunked fragment layout for an R x 256 bf16 matrix:
//   chunk id = (r>>4)*8 + (c>>5); 512 us per chunk;
//   interior = (((c&31)>>3)*16 + (r&15))*8 + (c&7) == lane*8 + j. Every MFMA
//   fragment is 64 lanes x 16 B contiguous -> 1 KB coalesced / conflict-free.

// ---------------------------------------------------------------------------
// Phase A: GroupNorm partial stats (vb 0..255) + weight fp32->bf16 chunked
// conversion (vb 256..511).
// ---------------------------------------------------------------------------
static __device__ void prep_phase(int vb, int tid, char* smem,
    const float* __restrict__ x, const float* __restrict__ w_qkv,
    const float* __restrict__ w_proj, float* __restrict__ partials,
    unsigned short* __restrict__ wbf)
{
    if (vb >= 256) {
        int idx = ((vb - 256)*256 + tid) * 4;     // 0..262140
        float4 v;
        if (idx < 196608) v = *(const float4*)(w_qkv + idx);
        else              v = *(const float4*)(w_proj + (idx - 196608));
        us4 h = { f2bf(v.x), f2bf(v.y), f2bf(v.z), f2bf(v.w) };
        int o = idx >> 8, c = idx & 255;
        size_t dst = ((size_t)((o >> 4)*8 + (c >> 5)))*512
                   + ((((c & 31) >> 3))*16 + (o & 15))*8 + (c & 7);
        *(us4*)(wbf + dst) = h;
        return;
    }
    const int bg = vb >> 3, slice = vb & 7;
    const float4* base = (const float4*)(x + (size_t)bg*CPG*NN + slice*16384);
    float s = 0.f, sq = 0.f;
    for (int i = tid; i < 4096; i += 256) {
        float4 v = base[i];
        s  += v.x + v.y + v.z + v.w;
        sq += v.x*v.x + v.y*v.y + v.z*v.z + v.w*v.w;
    }
    float* ls = (float*)smem;          // 1 KB
    float* lq = ls + 256;              // 1 KB
    ls[tid] = s; lq[tid] = sq;
    __syncthreads();
    for (int off = 128; off > 0; off >>= 1) {
        if (tid < off) { ls[tid] += ls[tid+off]; lq[tid] += lq[tid+off]; }
        __syncthreads();
    }
    if (tid == 0) { partials[vb*2] = ls[0]; partials[vb*2+1] = lq[0]; }
}

// ---------------------------------------------------------------------------
// Phase B: normalize + transpose: x -> xnT chunked bf16. vb in [0,1024).
// ---------------------------------------------------------------------------
static __device__ void norm_phase(int vb, int tid, char* smem,
    const float* __restrict__ x, const float* __restrict__ gamma,
    const float* __restrict__ beta, const float* __restrict__ partials,
    unsigned short* __restrict__ xnT)
{
    const int n0 = (vb & 63) * 64;
    const int c0 = ((vb >> 6) & 3) * 64;
    const int b  = vb >> 8;
    unsigned short* T = (unsigned short*)smem;          // 64*68 us = 8704 B
    float* ssc = (float*)(smem + 8704);                 // 256 B
    float* ssh = (float*)(smem + 8960);                 // 256 B
    if (tid < 64) {
        int c = c0 + tid;
        int bg = b*GG + (c >> 5);
        float s = 0.f, sq = 0.f;
        for (int i = 0; i < 8; i++) {
            s  += partials[(bg*8 + i)*2];
            sq += partials[(bg*8 + i)*2 + 1];
        }
        const float cnt = (float)(CPG*NN);
        float mean = s / cnt;
        float var  = sq / cnt - mean*mean;
        float rstd = rsqrtf(var + EPSV);
        float g = gamma[c], be = beta[c];
        ssc[tid] = rstd*g;
        ssh[tid] = be - mean*rstd*g;
    }
    __syncthreads();
    {
        int cl = tid >> 4, n4 = tid & 15;
        for (int i = 0; i < 4; i++) {
            int c = cl + i*16;
            float4 v = *(const float4*)(x + ((size_t)(b*CC + c0 + c))*NN + n0 + n4*4);
            float sc = ssc[c], sh = ssh[c];
            T[(n4*4+0)*68 + c] = f2bf(v.x*sc + sh);
            T[(n4*4+1)*68 + c] = f2bf(v.y*sc + sh);
            T[(n4*4+2)*68 + c] = f2bf(v.z*sc + sh);
            T[(n4*4+3)*68 + c] = f2bf(v.w*sc + sh);
        }
    }
    __syncthreads();
    {
        int nl = tid >> 3, cs = tid & 7;
        for (int i = 0; i < 2; i++) {
            int n = nl + i*32;                       // block-local row
            int gg = (b*NN + n0 + n) >> 4;           // global 16-row group
            int kk = (c0 >> 5) + (cs >> 2);          // 32-col group
            size_t dst = ((size_t)(gg*8 + kk))*512 + ((cs & 3)*16 + (n & 15))*8;
            *(bf16x8*)(xnT + dst) = *(const bf16x8*)&T[n*68 + cs*8];
        }
    }
}

// ---------------------------------------------------------------------------
// Phase C: QKV MFMA GEMM with async16 staging (R9 structure). vb in [0,1536):
// bxx = vb & 127 (row block), by = vb >> 7 (o block 0..11).
// ---------------------------------------------------------------------------
static __device__ void qkv_phase(int vb, int tid, char* smem,
    const unsigned short* __restrict__ xnT, const unsigned short* __restrict__ wbf,
    const float* __restrict__ b_qkv,
    unsigned short* __restrict__ qsw, unsigned short* __restrict__ ksw,
    unsigned short* __restrict__ vsw)
{
    const int wave = tid >> 6, lane = tid & 63;
    const int lrow = lane & 15, quad = lane >> 4;
    const int bxx  = vb & 127;
    const int R0   = bxx * 128;
    const int b    = bxx >> 5;
    const int nb0  = (bxx & 31) * 128;
    const int oBase = (vb >> 7) * 64;
    const int which = oBase >> 8;
    const int o0l   = oBase & 255;
    const bool isV  = (which == 2);
    const int wn = wave >> 1, wo = wave & 1;
    const int wg0 = oBase >> 4;                    // weight 16-row group base

    unsigned short* lw = (unsigned short*)smem;            // 32 KB
    unsigned short* lx0 = (unsigned short*)(smem + 32768); // 8 KB
    unsigned short* lx1 = (unsigned short*)(smem + 40960); // 8 KB
    unsigned short* lxx[2] = { lx0, lx1 };

    // prologue: stage weights (8 chunks/wave) + xnT kk=0 tile (2 chunks/wave)
    const unsigned short* wsrc = wbf + ((size_t)(wg0 + wave))*8*512 + lane*8;
    for (int kk = 0; kk < 8; kk++)
        async16(wsrc + kk*512, lw + (wave*8 + kk)*512);
    const unsigned short* xsrc = xnT + (size_t)R0*CC + lane*8;
    for (int i = 0; i < 2; i++) {
        int g = wave*2 + i;
        async16(xsrc + (size_t)g*4096, lx0 + g*512);
    }
    asm volatile("s_waitcnt vmcnt(0)" ::: "memory");
    __builtin_amdgcn_s_barrier();

    f32x4 acc[4][2];
    for (int s = 0; s < 4; s++) for (int t = 0; t < 2; t++)
        acc[s][t] = (f32x4){0.f, 0.f, 0.f, 0.f};

    for (int kk = 0; kk < 8; kk++) {
        const int cur = kk & 1, nxt = cur ^ 1;
        if (kk + 1 < 8) {
            for (int i = 0; i < 2; i++) {
                int g = wave*2 + i;
                async16(xsrc + (size_t)g*4096 + (kk+1)*512, lxx[nxt] + g*512);
            }
        }
        bf16x8 af[4], bfr[2];
        if (!isV) {
            for (int s = 0; s < 4; s++)
                af[s]  = *(const bf16x8*)(lw + (s*8 + kk)*512 + lane*8);
            for (int t = 0; t < 2; t++)
                bfr[t] = *(const bf16x8*)(lxx[cur] + (wave*2 + t)*512 + lane*8);
        } else {
            for (int s = 0; s < 4; s++)
                af[s]  = *(const bf16x8*)(lxx[cur] + (wn*4 + s)*512 + lane*8);
            for (int t = 0; t < 2; t++)
                bfr[t] = *(const bf16x8*)(lw + ((wo*2 + t)*8 + kk)*512 + lane*8);
        }
        __builtin_amdgcn_s_setprio(1);
        for (int s = 0; s < 4; s++)
            for (int t = 0; t < 2; t++)
                acc[s][t] = __builtin_amdgcn_mfma_f32_16x16x32_bf16(af[s], bfr[t], acc[s][t], 0, 0, 0);
        __builtin_amdgcn_s_setprio(0);
        asm volatile("s_waitcnt vmcnt(0) lgkmcnt(0)" ::: "memory");
        __builtin_amdgcn_s_barrier();
    }

    // epilogue: reuse lw as 8192-us scratch
    unsigned short* lds = lw;

    if (!isV) {
        const float sc = (which == 0) ? SCALE : 1.0f;
        for (int s = 0; s < 4; s++) {
            float bias[4];
            for (int r = 0; r < 4; r++) bias[r] = b_qkv[oBase + s*16 + quad*4 + r];
            for (int t = 0; t < 2; t++) {
                us4 h;
                h.x = f2bf((acc[s][t][0] + bias[0]) * sc);
                h.y = f2bf((acc[s][t][1] + bias[1]) * sc);
                h.z = f2bf((acc[s][t][2] + bias[2]) * sc);
                h.w = f2bf((acc[s][t][3] + bias[3]) * sc);
                int chunk = (wave*2 + t)*2 + (s>>1);
                int pos = (((s*2 + (quad>>1)) & 3)*16 + lrow)*8 + (quad&1)*4;
                *(us4*)&lds[chunk*512 + pos] = h;
            }
        }
    } else {
        for (int s = 0; s < 4; s++)
            for (int t = 0; t < 2; t++) {
                int oc = o0l + wo*32 + t*16 + lrow;
                float bias = b_qkv[512 + oc];
                us4 h;
                h.x = f2bf(acc[s][t][0] + bias);
                h.y = f2bf(acc[s][t][1] + bias);
                h.z = f2bf(acc[s][t][2] + bias);
                h.w = f2bf(acc[s][t][3] + bias);
                int chunk = (wn*2 + (s>>1))*4 + wo*2 + t;
                int pos = (((s&1)*2 + (quad>>1))*16 + lrow)*8 + (quad&1)*4;
                *(us4*)&lds[chunk*512 + pos] = h;
            }
    }
    __syncthreads();

    if (!isV) {
        unsigned short* dst = (which == 0) ? qsw : ksw;
        for (int it = 0; it < 4; it++) {
            int f = it*4 + (tid>>6);
            int ng_l = f >> 1, kk_l = f & 1;
            size_t off = ((size_t)(b*256 + (nb0>>4) + ng_l)*8 + (o0l>>5) + kk_l)*512 + lane*8;
            *(bf16x8*)(dst + off) = *(const bf16x8*)&lds[f*512 + lane*8];
        }
    } else {
        for (int it = 0; it < 4; it++) {
            int f = it*4 + (tid>>6);
            int jg_l = f >> 2, ns_l = f & 3;
            size_t off = ((size_t)(b*128 + (nb0>>5) + jg_l)*16 + (o0l>>4) + ns_l)*512 + lane*8;
            *(bf16x8*)(vsw + off) = *(const bf16x8*)&lds[f*512 + lane*8];
        }
    }
}

// ---------------------------------------------------------------------------
// Phase D: MFMA flash attention — R2 structure verbatim. vb in [0,512).
// ---------------------------------------------------------------------------
static __device__ void attn_phase(int bx, int tid, char* smem,
    const unsigned short* __restrict__ qsw, const unsigned short* __restrict__ ksw,
    const unsigned short* __restrict__ vsw,
    unsigned short* __restrict__ opart, float* __restrict__ lpart)
{
    const int wave = tid >> 6, lane = tid & 63;
    const int lrow = lane & 15, quad = lane >> 4;
    const int split = bx & 3;
    const int ig    = (bx >> 2) & 31;
    const int b     = bx >> 7;
    const int i0w   = ig*128 + wave*32;
    const int koff  = split * (NN / NSPLIT);   // 0,1024,2048,3072
    const int NT    = (NN / NSPLIT) / 32;      // 32 tiles

    unsigned short* ldsK0 = (unsigned short*)smem;             // 16 KB
    unsigned short* ldsK1 = (unsigned short*)(smem + 16384);   // 16 KB
    unsigned short* ldsV0 = (unsigned short*)(smem + 32768);   // 16 KB
    unsigned short* ldsV1 = (unsigned short*)(smem + 49152);   // 16 KB
    unsigned short* ldsP  = (unsigned short*)(smem + 65536);   // 10240 B
    unsigned short* ldsKb[2] = { ldsK0, ldsK1 };
    unsigned short* ldsVb[2] = { ldsV0, ldsV1 };

    bf16x8 qf[2][8];
    {
        const unsigned short* qb = qsw + ((size_t)b << 20) + (size_t)i0w*256 + lane*8;
        for (int g = 0; g < 2; g++)
            for (int kk = 0; kk < 8; kk++)
                qf[g][kk] = *(const bf16x8*)(qb + g*4096 + kk*512);
    }

    f32x4 o_acc[2][16];
    for (int g = 0; g < 2; g++)
        for (int ns = 0; ns < 16; ns++)
            o_acc[g][ns] = (f32x4){0.f, 0.f, 0.f, 0.f};
    float lsum[2] = {0.f, 0.f};

    const unsigned short* kp = ksw + ((size_t)b << 20) + (size_t)koff*256 + wave*2048 + lane*8;
    const unsigned short* vp = vsw + ((size_t)b << 20) + (size_t)koff*256 + wave*2048 + lane*8;

    for (int t = 0; t < 4; t++) {
        async16(kp + t*512, ldsK0 + wave*2048 + t*512);
        async16(vp + t*512, ldsV0 + wave*2048 + t*512);
    }
    asm volatile("s_waitcnt vmcnt(0)" ::: "memory");
    __builtin_amdgcn_s_barrier();

    for (int jt = 0; jt < NT; jt++) {
        const int cur = jt & 1, nxt = cur ^ 1;

        if (jt + 1 < NT) {
            for (int t = 0; t < 4; t++) {
                async16(kp + (size_t)(jt+1)*8192 + t*512, ldsKb[nxt] + wave*2048 + t*512);
                async16(vp + (size_t)(jt+1)*8192 + t*512, ldsVb[nxt] + wave*2048 + t*512);
            }
        }

        // ---- S^T = K Q^T
        f32x4 s[2][2];
        for (int jg = 0; jg < 2; jg++)
            for (int g = 0; g < 2; g++)
                s[jg][g] = (f32x4){0.f, 0.f, 0.f, 0.f};
        const unsigned short* lk = ldsKb[cur];
        __builtin_amdgcn_s_setprio(1);
        for (int jg = 0; jg < 2; jg++)
            for (int kk = 0; kk < 8; kk++) {
                bf16x8 kf = *(const bf16x8*)(lk + (jg*8 + kk)*512 + lane*8);
                s[jg][0] = __builtin_amdgcn_mfma_f32_16x16x32_bf16(kf, qf[0][kk], s[jg][0], 0, 0, 0);
                s[jg][1] = __builtin_amdgcn_mfma_f32_16x16x32_bf16(kf, qf[1][kk], s[jg][1], 0, 0, 0);
            }
        __builtin_amdgcn_s_setprio(0);

        // ---- p = exp(s); packed b64 P writes (wave-private)
        unsigned short* pw = ldsP + wave*32*PSTR;
        for (int jg = 0; jg < 2; jg++)
            for (int g = 0; g < 2; g++) {
                float p0 = __expf(s[jg][g][0]);
                float p1 = __expf(s[jg][g][1]);
                float p2 = __expf(s[jg][g][2]);
                float p3 = __expf(s[jg][g][3]);
                lsum[g] += p0 + p1 + p2 + p3;
                us4 h = { f2bf(p0), f2bf(p1), f2bf(p2), f2bf(p3) };
                *(us4*)(pw + (g*16 + lrow)*PSTR + jg*16 + quad*4) = h;
            }

        bf16x8 pa[2];
        for (int g = 0; g < 2; g++)
            pa[g] = *(const bf16x8*)(pw + (g*16 + lrow)*PSTR + quad*8);

        const unsigned short* lv = ldsVb[cur];
        __builtin_amdgcn_s_setprio(1);
        for (int ns = 0; ns < 16; ns++) {
            bf16x8 vf = *(const bf16x8*)(lv + ns*512 + lane*8);
            o_acc[0][ns] = __builtin_amdgcn_mfma_f32_16x16x32_bf16(pa[0], vf, o_acc[0][ns], 0, 0, 0);
            o_acc[1][ns] = __builtin_amdgcn_mfma_f32_16x16x32_bf16(pa[1], vf, o_acc[1][ns], 0, 0, 0);
        }
        __builtin_amdgcn_s_setprio(0);

        asm volatile("s_waitcnt vmcnt(0) lgkmcnt(0)" ::: "memory");
        __builtin_amdgcn_s_barrier();
    }

    for (int g = 0; g < 2; g++) {
        float v = lsum[g];
        v += __shfl_xor(v, 16);
        v += __shfl_xor(v, 32);
        lsum[g] = v;
    }

    // epilogue: bounce O through LDS into frag-chunk layout, store b128.
    unsigned short* reg = ldsV0 + wave*4096;
    const size_t planeb = ((size_t)(split*BB + b)) << 20;
    for (int g = 0; g < 2; g++) {
        for (int ns = 0; ns < 16; ns++) {
            int kk = ns >> 1;
            int posbase = ((ns & 1)*2 + (lrow >> 3))*128 + (lrow & 7) + quad*32;
            for (int r = 0; r < 4; r++)
                reg[kk*512 + posbase + r*8] = f2bf(o_acc[g][ns][r]);
        }
        unsigned short* dst = opart + planeb + ((size_t)((i0w >> 4) + g))*4096;
        for (int kk = 0; kk < 8; kk++)
            *(bf16x8*)(dst + kk*512 + lane*8) = *(const bf16x8*)(reg + kk*512 + lane*8);
    }
    if (quad == 0)
        for (int g = 0; g < 2; g++)
            lpart[(size_t)(split*BB + b)*NN + i0w + g*16 + lrow] = lsum[g];
}

// ---------------------------------------------------------------------------
// Phase E: proj MFMA with wave-private async16 staging (R9 structure).
// vb in [0,1024): rt = vb & 255, oq = vb >> 8.
// ---------------------------------------------------------------------------
static __device__ void proj_phase(int vb, int tid, char* smem,
    const unsigned short* __restrict__ opart, const float* __restrict__ lpart,
    const unsigned short* __restrict__ w2bf, const float* __restrict__ b_proj,
    const float* __restrict__ x, float* __restrict__ out)
{
    const int wave = tid >> 6, lane = tid & 63;
    const int lrow = lane & 15, quad = lane >> 4;
    const int rt = vb & 255;
    const int oq = vb >> 8;
    const int b  = rt >> 6;
    const int n0 = (rt & 63) * 64;

    const int rg = (n0 >> 4) + wave;
    const unsigned short* Ab = opart + ((size_t)b << 20) + (size_t)rg*4096 + lane*8;
    const size_t pstride = (size_t)BB << 20;

    unsigned short* la0 = (unsigned short*)smem;            // 16 KB
    unsigned short* la1 = (unsigned short*)(smem + 16384);  // 16 KB
    unsigned short* lab[2] = { la0, la1 };

    for (int sp = 0; sp < NSPLIT; sp++)
        async16(Ab + (size_t)sp*pstride, la0 + (wave*4 + sp)*512);
    asm volatile("s_waitcnt vmcnt(0)" ::: "memory");

    f32x4 acc[4];
    for (int t = 0; t < 4; t++) acc[t] = (f32x4){0.f, 0.f, 0.f, 0.f};

    for (int kk = 0; kk < 8; kk++) {
        const int cur = kk & 1, nxt = cur ^ 1;
        if (kk + 1 < 8)
            for (int sp = 0; sp < NSPLIT; sp++)
                async16(Ab + (size_t)sp*pstride + (kk+1)*512, lab[nxt] + (wave*4 + sp)*512);

        bf16x8 bfr[4];
        for (int t = 0; t < 4; t++)
            bfr[t] = *(const bf16x8*)(w2bf + ((size_t)((oq*4 + t)*8 + kk))*512 + lane*8);

        __builtin_amdgcn_s_setprio(1);
        for (int sp = 0; sp < NSPLIT; sp++) {
            bf16x8 af = *(const bf16x8*)(lab[cur] + (wave*4 + sp)*512 + lane*8);
            for (int t = 0; t < 4; t++)
                acc[t] = __builtin_amdgcn_mfma_f32_16x16x32_bf16(af, bfr[t], acc[t], 0, 0, 0);
        }
        __builtin_amdgcn_s_setprio(0);

        asm volatile("s_waitcnt vmcnt(0)" ::: "memory");   // per-wave drain
    }

    float sinv[4];
    for (int r = 0; r < 4; r++) {
        int n = n0 + wave*16 + quad*4 + r;
        float l = 0.f;
        for (int sp = 0; sp < NSPLIT; sp++)
            l += lpart[(size_t)(sp*BB + b)*NN + n];
        sinv[r] = 1.0f / l;
    }

    for (int t = 0; t < 4; t++) {
        int o = oq*64 + t*16 + lrow;
        int n = n0 + wave*16 + quad*4;
        size_t idx = ((size_t)(b*CC + o))*NN + n;
        float bias = b_proj[o];
        float4 xv = *(const float4*)(x + idx);
        float4 ov;
        ov.x = acc[t][0]*sinv[0] + bias + xv.x;
        ov.y = acc[t][1]*sinv[1] + bias + xv.y;
        ov.z = acc[t][2]*sinv[2] + bias + xv.z;
        ov.w = acc[t][3]*sinv[3] + bias + xv.w;
        *(float4*)(out + idx) = ov;
    }
}

// ---------------------------------------------------------------------------
// R10: ONE cooperative kernel, 512 blocks x 256 threads (2 blocks/CU),
// phases separated by grid.sync(). Eliminates 4 inter-kernel launch gaps.
// ---------------------------------------------------------------------------
__global__ __launch_bounds__(256, 2) void fused_kernel(
    const float* x, const float* gamma, const float* beta,
    const float* w_qkv, const float* b_qkv, const float* w_proj,
    const float* b_proj, float* out, unsigned short* ws)
{
    __shared__ __align__(16) char smem[SMEM_BYTES];
    const int bid = blockIdx.x, tid = threadIdx.x;
    cg::grid_group grid = cg::this_grid();

    const size_t plane = (size_t)BB * NN * CC;
    unsigned short* xnT = ws;
    unsigned short* qsw = xnT + plane;
    unsigned short* ksw = qsw + plane;
    unsigned short* vsw = ksw + plane;
    unsigned short* wbf = vsw + plane;
    unsigned short* opart = wbf + 262144;
    float* lpart    = (float*)(opart + (size_t)NSPLIT*plane);
    float* partials = lpart + (size_t)NSPLIT*BB*NN;

    // A: prep (512 vblocks)
    prep_phase(bid, tid, smem, x, w_qkv, w_proj, partials, wbf);
    grid.sync();

    // B: norm+transpose (1024 vblocks)
    for (int v = bid; v < 1024; v += 512) {
        __syncthreads();
        norm_phase(v, tid, smem, x, gamma, beta, partials, xnT);
    }
    grid.sync();

    // C: qkv GEMM (1536 vblocks)
    for (int v = bid; v < 1536; v += 512) {
        __syncthreads();
        qkv_phase(v, tid, smem, xnT, wbf, b_qkv, qsw, ksw, vsw);
    }
    grid.sync();

    // D: attention (512 vblocks)
    attn_phase(bid, tid, smem, qsw, ksw, vsw, opart, lpart);
    grid.sync();

    // E: proj (1024 vblocks; wave-private LDS, no loop barrier needed)
    for (int v = bid; v < 1024; v += 512)
        proj_phase(v, tid, smem, opart, lpart, wbf + 196608, b_proj, x, out);
}

// ---------------------------------------------------------------------------
// Fallback standalone wrappers (byte-equivalent to R9 path).
// ---------------------------------------------------------------------------
__global__ __launch_bounds__(256) void prep_kernel(
    const float* __restrict__ x, const float* __restrict__ w_qkv,
    const float* __restrict__ w_proj, float* __restrict__ partials,
    unsigned short* __restrict__ wbf)
{
    __shared__ __align__(16) char smem[2048];
    prep_phase(blockIdx.x, threadIdx.x, smem, x, w_qkv, w_proj, partials, wbf);
}

__global__ __launch_bounds__(256) void norm_t_kernel(
    const float* __restrict__ x, const float* __restrict__ gamma,
    const float* __restrict__ beta, const float* __restrict__ partials,
    unsigned short* __restrict__ xnT)
{
    __shared__ __align__(16) char smem[9216];
    norm_phase(blockIdx.x, threadIdx.x, smem, x, gamma, beta, partials, xnT);
}

__global__ __launch_bounds__(256, 3) void qkv_mfma_kernel(
    const unsigned short* __restrict__ xnT, const unsigned short* __restrict__ wbf,
    const float* __restrict__ b_qkv,
    unsigned short* __restrict__ qsw, unsigned short* __restrict__ ksw,
    unsigned short* __restrict__ vsw)
{
    __shared__ __align__(16) char smem[49152];
    qkv_phase(blockIdx.x, threadIdx.x, smem, xnT, wbf, b_qkv, qsw, ksw, vsw);
}

__global__ __launch_bounds__(256, 2) void attn_mfma_kernel(
    const unsigned short* __restrict__ qsw, const unsigned short* __restrict__ ksw,
    const unsigned short* __restrict__ vsw,
    unsigned short* __restrict__ opart, float* __restrict__ lpart)
{
    __shared__ __align__(16) char smem[SMEM_BYTES];
    attn_phase(blockIdx.x, threadIdx.x, smem, qsw, ksw, vsw, opart, lpart);
}

__global__ __launch_bounds__(256, 4) void proj_mfma_kernel(
    const unsigned short* __restrict__ opart, const float* __restrict__ lpart,
    const unsigned short* __restrict__ w2bf, const float* __restrict__ b_proj,
    const float* __restrict__ x, float* __restrict__ out)
{
    __shared__ __align__(16) char smem[32768];
    proj_phase(blockIdx.x, threadIdx.x, smem, opart, lpart, w2bf, b_proj, x, out);
}

// ---------------------------------------------------------------------------
extern "C" void kernel_launch(void* const* d_in, const int* in_sizes, int n_in,
                              void* d_out, int out_size, void* d_ws, size_t ws_size,
                              hipStream_t stream) {
    const float* x      = (const float*)d_in[0];
    const float* gamma  = (const float*)d_in[1];
    const float* beta   = (const float*)d_in[2];
    const float* w_qkv  = (const float*)d_in[3];
    const float* b_qkv  = (const float*)d_in[4];
    const float* w_proj = (const float*)d_in[5];
    const float* b_proj = (const float*)d_in[6];
    float* out = (float*)d_out;
    unsigned short* ws = (unsigned short*)d_ws;

    void* kargs[] = { (void*)&x, (void*)&gamma, (void*)&beta, (void*)&w_qkv,
                      (void*)&b_qkv, (void*)&w_proj, (void*)&b_proj,
                      (void*)&out, (void*)&ws };
    hipError_t err = hipLaunchCooperativeKernel(
        (const void*)fused_kernel, dim3(512), dim3(256), kargs, 0, stream);

    if (err != hipSuccess) {
        (void)hipGetLastError();   // clear error, take the 5-kernel R9 path
        const size_t plane = (size_t)BB * NN * CC;
        unsigned short* xnT = ws;
        unsigned short* qsw = xnT + plane;
        unsigned short* ksw = qsw + plane;
        unsigned short* vsw = ksw + plane;
        unsigned short* wbf = vsw + plane;
        unsigned short* opart = wbf + 262144;
        float* lpart    = (float*)(opart + (size_t)NSPLIT*plane);
        float* partials = lpart + (size_t)NSPLIT*BB*NN;

        prep_kernel<<<512, 256, 0, stream>>>(x, w_qkv, w_proj, partials, wbf);
        norm_t_kernel<<<1024, 256, 0, stream>>>(x, gamma, beta, partials, xnT);
        qkv_mfma_kernel<<<1536, 256, 0, stream>>>(xnT, wbf, b_qkv, qsw, ksw, vsw);
        attn_mfma_kernel<<<512, 256, 0, stream>>>(qsw, ksw, vsw, opart, lpart);
        proj_mfma_kernel<<<1024, 256, 0, stream>>>(opart, lpart, wbf + 196608, b_proj, x, out);
    }
}

// Round 11
// 187.697 us; speedup vs baseline: 2.4345x; 2.4345x over previous
//
#include <hip/hip_runtime.h>
#include <math.h>

// Problem constants: x [4, 256, 64, 64] fp32
#define BB   4
#define CC   256
#define NN   4096      // 64*64 spatial
#define GG   8
#define CPG  32        // channels per group
#define EPSV 1e-5f
#define SCALE 0.0625f  // 1/sqrt(256)
#define NSPLIT 4
#define PSTR 40        // ldsP row stride in ushorts (80 B: 16B-aligned rows)

typedef __attribute__((ext_vector_type(8))) short bf16x8;  // 8 bf16 = 4 VGPRs
typedef __attribute__((ext_vector_type(4))) float f32x4;

struct alignas(8) us4 { unsigned short x, y, z, w; };

static __device__ __forceinline__ unsigned short f2bf(float f) {
    union { float f; unsigned int u; } a; a.f = f;
    unsigned int r = a.u + 0x7fffu + ((a.u >> 16) & 1u);   // RNE
    return (unsigned short)(r >> 16);
}
// async global->LDS, 16B/lane: per-lane gptr, wave-uniform LDS base (+lane*16 by HW)
static __device__ __forceinline__ void async16(const unsigned short* g, unsigned short* l) {
    __builtin_amdgcn_global_load_lds(
        (const __attribute__((address_space(1))) unsigned int*)g,
        (__attribute__((address_space(3))) unsigned int*)l,
        16, 0, 0);
}

// Chunked fragment layout for an R x 256 bf16 matrix:
//   chunk id = (r>>4)*8 + (c>>5); 512 us per chunk;
//   interior  = (((c&31)>>3)*16 + (r&15))*8 + (c&7)   == lane*8 + j for the
//   MFMA fragment (lane = (r&15) | ((c&31)>>3)<<4).  Every fragment is 64
//   lanes x 16 B contiguous -> 1 KB coalesced loads / conflict-free ds_reads.

// ---------------------------------------------------------------------------
// K0: merged prep: blocks 0..255 = GroupNorm partial stats; 256..511 = weight
// fp32->bf16 conversion into CHUNKED layout (w_qkv 768x256 then w_proj 256x256
// as one 1024-row chunked matrix; proj weights start at us offset 196608).
// ---------------------------------------------------------------------------
__global__ __launch_bounds__(256) void prep_kernel(
    const float* __restrict__ x, const float* __restrict__ w_qkv,
    const float* __restrict__ w_proj, float* __restrict__ partials,
    unsigned short* __restrict__ wbf)
{
    const int tid = threadIdx.x;
    if (blockIdx.x >= 256) {
        int idx = ((blockIdx.x - 256)*256 + tid) * 4;     // 0..262140
        float4 v;
        if (idx < 196608) v = *(const float4*)(w_qkv + idx);
        else              v = *(const float4*)(w_proj + (idx - 196608));
        us4 h = { f2bf(v.x), f2bf(v.y), f2bf(v.z), f2bf(v.w) };
        int o = idx >> 8, c = idx & 255;
        size_t dst = ((size_t)((o >> 4)*8 + (c >> 5)))*512
                   + ((((c & 31) >> 3))*16 + (o & 15))*8 + (c & 7);
        *(us4*)(wbf + dst) = h;
        return;
    }
    const int bg = blockIdx.x >> 3, slice = blockIdx.x & 7;
    const float4* base = (const float4*)(x + (size_t)bg*CPG*NN + slice*16384);
    float s = 0.f, sq = 0.f;
    for (int i = tid; i < 4096; i += 256) {
        float4 v = base[i];
        s  += v.x + v.y + v.z + v.w;
        sq += v.x*v.x + v.y*v.y + v.z*v.z + v.w*v.w;
    }
    __shared__ float ls[256], lq[256];
    ls[tid] = s; lq[tid] = sq;
    __syncthreads();
    for (int off = 128; off > 0; off >>= 1) {
        if (tid < off) { ls[tid] += ls[tid+off]; lq[tid] += lq[tid+off]; }
        __syncthreads();
    }
    if (tid == 0) { partials[blockIdx.x*2] = ls[0]; partials[blockIdx.x*2+1] = lq[0]; }
}

// ---------------------------------------------------------------------------
// K2: normalize + transpose: x [b][c][n] fp32 -> xnT CHUNKED bf16.
// Row index of xnT = b*4096 + n; chunk = (row>>4)*8 + (c>>5).
// ---------------------------------------------------------------------------
__global__ __launch_bounds__(256) void norm_t_kernel(
    const float* __restrict__ x, const float* __restrict__ gamma,
    const float* __restrict__ beta, const float* __restrict__ partials,
    unsigned short* __restrict__ xnT)
{
    const int n0 = blockIdx.x * 64;
    const int c0 = blockIdx.y * 64;
    const int b  = blockIdx.z;
    const int tid = threadIdx.x;
    __shared__ unsigned short T[64*68];
    __shared__ float ssc[64], ssh[64];
    if (tid < 64) {
        int c = c0 + tid;
        int bg = b*GG + (c >> 5);
        float s = 0.f, sq = 0.f;
        for (int i = 0; i < 8; i++) {
            s  += partials[(bg*8 + i)*2];
            sq += partials[(bg*8 + i)*2 + 1];
        }
        const float cnt = (float)(CPG*NN);
        float mean = s / cnt;
        float var  = sq / cnt - mean*mean;
        float rstd = rsqrtf(var + EPSV);
        float g = gamma[c], be = beta[c];
        ssc[tid] = rstd*g;
        ssh[tid] = be - mean*rstd*g;
    }
    __syncthreads();
    {
        int cl = tid >> 4, n4 = tid & 15;
        for (int i = 0; i < 4; i++) {
            int c = cl + i*16;
            float4 v = *(const float4*)(x + ((size_t)(b*CC + c0 + c))*NN + n0 + n4*4);
            float sc = ssc[c], sh = ssh[c];
            T[(n4*4+0)*68 + c] = f2bf(v.x*sc + sh);
            T[(n4*4+1)*68 + c] = f2bf(v.y*sc + sh);
            T[(n4*4+2)*68 + c] = f2bf(v.z*sc + sh);
            T[(n4*4+3)*68 + c] = f2bf(v.w*sc + sh);
        }
    }
    __syncthreads();
    {
        int nl = tid >> 3, cs = tid & 7;
        for (int i = 0; i < 2; i++) {
            int n = nl + i*32;                       // block-local row
            int gg = (b*NN + n0 + n) >> 4;           // global 16-row group
            int kk = (c0 >> 5) + (cs >> 2);          // 32-col group
            size_t dst = ((size_t)(gg*8 + kk))*512 + ((cs & 3)*16 + (n & 15))*8;
            *(bf16x8*)(xnT + dst) = *(const bf16x8*)&T[n*68 + cs*8];
        }
    }
}

// ---------------------------------------------------------------------------
// K3: QKV MFMA GEMM, R9 structure: async16 DMA staging (attn-style).
// ---------------------------------------------------------------------------
__global__ __launch_bounds__(256, 3) void qkv_mfma_kernel(
    const unsigned short* __restrict__ xnT, const unsigned short* __restrict__ wbf,
    const float* __restrict__ b_qkv,
    unsigned short* __restrict__ qsw, unsigned short* __restrict__ ksw,
    unsigned short* __restrict__ vsw)
{
    const int tid  = threadIdx.x;
    const int wave = tid >> 6, lane = tid & 63;
    const int lrow = lane & 15, quad = lane >> 4;
    const int R0   = blockIdx.x * 128;
    const int b    = blockIdx.x >> 5;
    const int nb0  = (blockIdx.x & 31) * 128;
    const int oBase = blockIdx.y * 64;
    const int which = oBase >> 8;
    const int o0l   = oBase & 255;
    const bool isV  = (which == 2);
    const int wn = wave >> 1, wo = wave & 1;
    const int wg0 = oBase >> 4;                    // weight 16-row group base

    __shared__ unsigned short lw[16384];           // 32 KB: weights (4g x 8kk)
    __shared__ unsigned short lx[2][4096];         // 16 KB: xnT kk-tile dbuf

    // prologue: stage weights (8 chunks/wave) + xnT kk=0 tile (2 chunks/wave)
    const unsigned short* wsrc = wbf + ((size_t)(wg0 + wave))*8*512 + lane*8;
    for (int kk = 0; kk < 8; kk++)
        async16(wsrc + kk*512, lw + (wave*8 + kk)*512);
    const unsigned short* xsrc = xnT + (size_t)R0*CC + lane*8;   // == (R0>>4)*8*512
    for (int i = 0; i < 2; i++) {
        int g = wave*2 + i;
        async16(xsrc + (size_t)g*4096, lx[0] + g*512);
    }
    asm volatile("s_waitcnt vmcnt(0)" ::: "memory");
    __builtin_amdgcn_s_barrier();

    f32x4 acc[4][2];
    for (int s = 0; s < 4; s++) for (int t = 0; t < 2; t++)
        acc[s][t] = (f32x4){0.f, 0.f, 0.f, 0.f};

    for (int kk = 0; kk < 8; kk++) {
        const int cur = kk & 1, nxt = cur ^ 1;
        if (kk + 1 < 8) {
            for (int i = 0; i < 2; i++) {
                int g = wave*2 + i;
                async16(xsrc + (size_t)g*4096 + (kk+1)*512, lx[nxt] + g*512);
            }
        }
        bf16x8 af[4], bfr[2];
        if (!isV) {
            for (int s = 0; s < 4; s++)
                af[s]  = *(const bf16x8*)(lw + (s*8 + kk)*512 + lane*8);
            for (int t = 0; t < 2; t++)
                bfr[t] = *(const bf16x8*)(lx[cur] + (wave*2 + t)*512 + lane*8);
        } else {
            for (int s = 0; s < 4; s++)
                af[s]  = *(const bf16x8*)(lx[cur] + (wn*4 + s)*512 + lane*8);
            for (int t = 0; t < 2; t++)
                bfr[t] = *(const bf16x8*)(lw + ((wo*2 + t)*8 + kk)*512 + lane*8);
        }
        __builtin_amdgcn_s_setprio(1);
        for (int s = 0; s < 4; s++)
            for (int t = 0; t < 2; t++)
                acc[s][t] = __builtin_amdgcn_mfma_f32_16x16x32_bf16(af[s], bfr[t], acc[s][t], 0, 0, 0);
        __builtin_amdgcn_s_setprio(0);
        asm volatile("s_waitcnt vmcnt(0) lgkmcnt(0)" ::: "memory");
        __builtin_amdgcn_s_barrier();
    }

    // epilogue (unchanged semantics): reuse lw as 8192-us scratch
    unsigned short* lds = lw;

    if (!isV) {
        const float sc = (which == 0) ? SCALE : 1.0f;
        for (int s = 0; s < 4; s++) {
            float bias[4];
            for (int r = 0; r < 4; r++) bias[r] = b_qkv[oBase + s*16 + quad*4 + r];
            for (int t = 0; t < 2; t++) {
                us4 h;
                h.x = f2bf((acc[s][t][0] + bias[0]) * sc);
                h.y = f2bf((acc[s][t][1] + bias[1]) * sc);
                h.z = f2bf((acc[s][t][2] + bias[2]) * sc);
                h.w = f2bf((acc[s][t][3] + bias[3]) * sc);
                int chunk = (wave*2 + t)*2 + (s>>1);
                int pos = (((s*2 + (quad>>1)) & 3)*16 + lrow)*8 + (quad&1)*4;
                *(us4*)&lds[chunk*512 + pos] = h;
            }
        }
    } else {
        for (int s = 0; s < 4; s++)
            for (int t = 0; t < 2; t++) {
                int oc = o0l + wo*32 + t*16 + lrow;
                float bias = b_qkv[512 + oc];
                us4 h;
                h.x = f2bf(acc[s][t][0] + bias);
                h.y = f2bf(acc[s][t][1] + bias);
                h.z = f2bf(acc[s][t][2] + bias);
                h.w = f2bf(acc[s][t][3] + bias);
                int chunk = (wn*2 + (s>>1))*4 + wo*2 + t;
                int pos = (((s&1)*2 + (quad>>1))*16 + lrow)*8 + (quad&1)*4;
                *(us4*)&lds[chunk*512 + pos] = h;
            }
    }
    __syncthreads();

    if (!isV) {
        unsigned short* dst = (which == 0) ? qsw : ksw;
        for (int it = 0; it < 4; it++) {
            int f = it*4 + (tid>>6);
            int ng_l = f >> 1, kk_l = f & 1;
            size_t off = ((size_t)(b*256 + (nb0>>4) + ng_l)*8 + (o0l>>5) + kk_l)*512 + lane*8;
            *(bf16x8*)(dst + off) = *(const bf16x8*)&lds[f*512 + lane*8];
        }
    } else {
        for (int it = 0; it < 4; it++) {
            int f = it*4 + (tid>>6);
            int jg_l = f >> 2, ns_l = f & 3;
            size_t off = ((size_t)(b*128 + (nb0>>5) + jg_l)*16 + (o0l>>4) + ns_l)*512 + lane*8;
            *(bf16x8*)(vsw + off) = *(const bf16x8*)&lds[f*512 + lane*8];
        }
    }
}

// ---------------------------------------------------------------------------
// K4: MFMA flash attention — R2 compute structure + R11 XCD-locality swizzle.
// bid decomposition: slice = bx & 15 (b*4+split), ig = bx >> 4. All 32 blocks
// of one (b,split) slice share bx%8 -> same XCD (round-robin dispatch), so
// each XCD streams only 2 slices = 2 MB of K+V -> fully L2-resident after
// first pass (was: all 16 slices = 16 MB thrash through 4 MB L2, forcing
// ~1 GB of L3 traffic at ~13 TB/s = the measured 82 us).
// ---------------------------------------------------------------------------
__global__ __launch_bounds__(256, 2) void attn_mfma_kernel(
    const unsigned short* __restrict__ qsw, const unsigned short* __restrict__ ksw,
    const unsigned short* __restrict__ vsw,
    unsigned short* __restrict__ opart, float* __restrict__ lpart)
{
    const int tid  = threadIdx.x;
    const int wave = tid >> 6, lane = tid & 63;
    const int lrow = lane & 15, quad = lane >> 4;
    const int bx    = blockIdx.x;
    const int sl    = bx & 15;                 // slice id (b*4 + split)
    const int ig    = bx >> 4;                 // 0..31
    const int split = sl & 3;
    const int b     = sl >> 2;
    const int i0w   = ig*128 + wave*32;
    const int koff  = split * (NN / NSPLIT);   // 0,1024,2048,3072
    const int NT    = (NN / NSPLIT) / 32;      // 32 tiles

    __shared__ unsigned short ldsK[2][8192];       // 32 KB: K double buf
    __shared__ unsigned short ldsV[2][8192];       // 32 KB: V double buf
    __shared__ unsigned short ldsP[4][32*PSTR];    // 10 KB (wave-private rows)

    bf16x8 qf[2][8];
    {
        const unsigned short* qb = qsw + ((size_t)b << 20) + (size_t)i0w*256 + lane*8;
        for (int g = 0; g < 2; g++)
            for (int kk = 0; kk < 8; kk++)
                qf[g][kk] = *(const bf16x8*)(qb + g*4096 + kk*512);
    }

    f32x4 o_acc[2][16];
    for (int g = 0; g < 2; g++)
        for (int ns = 0; ns < 16; ns++)
            o_acc[g][ns] = (f32x4){0.f, 0.f, 0.f, 0.f};
    float lsum[2] = {0.f, 0.f};

    const unsigned short* kp = ksw + ((size_t)b << 20) + (size_t)koff*256 + wave*2048 + lane*8;
    const unsigned short* vp = vsw + ((size_t)b << 20) + (size_t)koff*256 + wave*2048 + lane*8;

    // prologue: stage tile 0 into buffer 0
    for (int t = 0; t < 4; t++) {
        async16(kp + t*512, ldsK[0] + wave*2048 + t*512);
        async16(vp + t*512, ldsV[0] + wave*2048 + t*512);
    }
    asm volatile("s_waitcnt vmcnt(0)" ::: "memory");
    __builtin_amdgcn_s_barrier();

    for (int jt = 0; jt < NT; jt++) {
        const int cur = jt & 1, nxt = cur ^ 1;

        if (jt + 1 < NT) {
            for (int t = 0; t < 4; t++) {
                async16(kp + (size_t)(jt+1)*8192 + t*512, ldsK[nxt] + wave*2048 + t*512);
                async16(vp + (size_t)(jt+1)*8192 + t*512, ldsV[nxt] + wave*2048 + t*512);
            }
        }

        // ---- S^T = K Q^T
        f32x4 s[2][2];   // [jg key-group][g query-group]
        for (int jg = 0; jg < 2; jg++)
            for (int g = 0; g < 2; g++)
                s[jg][g] = (f32x4){0.f, 0.f, 0.f, 0.f};
        const unsigned short* lk = ldsK[cur];
        __builtin_amdgcn_s_setprio(1);
        for (int jg = 0; jg < 2; jg++)
            for (int kk = 0; kk < 8; kk++) {
                bf16x8 kf = *(const bf16x8*)(lk + (jg*8 + kk)*512 + lane*8);
                s[jg][0] = __builtin_amdgcn_mfma_f32_16x16x32_bf16(kf, qf[0][kk], s[jg][0], 0, 0, 0);
                s[jg][1] = __builtin_amdgcn_mfma_f32_16x16x32_bf16(kf, qf[1][kk], s[jg][1], 0, 0, 0);
            }
        __builtin_amdgcn_s_setprio(0);

        // ---- p = exp(s); packed b64 P writes (wave-private); per-lane l partials
        unsigned short* pw = ldsP[wave];
        for (int jg = 0; jg < 2; jg++)
            for (int g = 0; g < 2; g++) {
                float p0 = __expf(s[jg][g][0]);
                float p1 = __expf(s[jg][g][1]);
                float p2 = __expf(s[jg][g][2]);
                float p3 = __expf(s[jg][g][3]);
                lsum[g] += p0 + p1 + p2 + p3;
                us4 h = { f2bf(p0), f2bf(p1), f2bf(p2), f2bf(p3) };
                *(us4*)(pw + (g*16 + lrow)*PSTR + jg*16 + quad*4) = h;
            }

        // P read-back (same wave; compiler orders via lgkmcnt)
        bf16x8 pa[2];
        for (int g = 0; g < 2; g++)
            pa[g] = *(const bf16x8*)(pw + (g*16 + lrow)*PSTR + quad*8);

        const unsigned short* lv = ldsV[cur];
        __builtin_amdgcn_s_setprio(1);
        for (int ns = 0; ns < 16; ns++) {
            bf16x8 vf = *(const bf16x8*)(lv + ns*512 + lane*8);
            o_acc[0][ns] = __builtin_amdgcn_mfma_f32_16x16x32_bf16(pa[0], vf, o_acc[0][ns], 0, 0, 0);
            o_acc[1][ns] = __builtin_amdgcn_mfma_f32_16x16x32_bf16(pa[1], vf, o_acc[1][ns], 0, 0, 0);
        }
        __builtin_amdgcn_s_setprio(0);

        asm volatile("s_waitcnt vmcnt(0) lgkmcnt(0)" ::: "memory");
        __builtin_amdgcn_s_barrier();
    }

    for (int g = 0; g < 2; g++) {
        float v = lsum[g];
        v += __shfl_xor(v, 16);
        v += __shfl_xor(v, 32);
        lsum[g] = v;
    }

    // epilogue: bounce O through LDS into frag-chunk layout, store b128.
    unsigned short* reg = &ldsV[0][0] + wave*4096;
    const size_t planeb = ((size_t)(split*BB + b)) << 20;
    for (int g = 0; g < 2; g++) {
        for (int ns = 0; ns < 16; ns++) {
            int kk = ns >> 1;
            int posbase = ((ns & 1)*2 + (lrow >> 3))*128 + (lrow & 7) + quad*32;
            for (int r = 0; r < 4; r++)
                reg[kk*512 + posbase + r*8] = f2bf(o_acc[g][ns][r]);
        }
        unsigned short* dst = opart + planeb + ((size_t)((i0w >> 4) + g))*4096;
        for (int kk = 0; kk < 8; kk++)
            *(bf16x8*)(dst + kk*512 + lane*8) = *(const bf16x8*)(reg + kk*512 + lane*8);
    }
    if (quad == 0)
        for (int g = 0; g < 2; g++)
            lpart[(size_t)(split*BB + b)*NN + i0w + g*16 + lrow] = lsum[g];
}

// ---------------------------------------------------------------------------
// K5: proj MFMA, R9 structure: async16 staging of opart (wave-private,
// no barriers). Block = 64 n x 64 o, grid 1024, 4 blocks/CU.
// ---------------------------------------------------------------------------
__global__ __launch_bounds__(256, 4) void proj_mfma_kernel(
    const unsigned short* __restrict__ opart, const float* __restrict__ lpart,
    const unsigned short* __restrict__ w2bf, const float* __restrict__ b_proj,
    const float* __restrict__ x, float* __restrict__ out)
{
    const int tid  = threadIdx.x;
    const int wave = tid >> 6, lane = tid & 63;
    const int lrow = lane & 15, quad = lane >> 4;
    const int rt = blockIdx.x & 255;           // row-tile (64 rows)
    const int oq = blockIdx.x >> 8;            // o-quarter (64 outs)
    const int b  = rt >> 6;
    const int n0 = (rt & 63) * 64;

    const int rg = (n0 >> 4) + wave;           // 16-row group within batch
    const unsigned short* Ab = opart + ((size_t)b << 20) + (size_t)rg*4096 + lane*8;
    const size_t pstride = (size_t)BB << 20;   // split-plane stride (us)

    __shared__ unsigned short la[2][8192];     // 32 KB dbuf: 16 chunks (w*4+sp)

    // prologue: stage kk=0 (wave-private: own rg, 4 split planes)
    for (int sp = 0; sp < NSPLIT; sp++)
        async16(Ab + (size_t)sp*pstride, la[0] + (wave*4 + sp)*512);
    asm volatile("s_waitcnt vmcnt(0)" ::: "memory");

    f32x4 acc[4];
    for (int t = 0; t < 4; t++) acc[t] = (f32x4){0.f, 0.f, 0.f, 0.f};

    for (int kk = 0; kk < 8; kk++) {
        const int cur = kk & 1, nxt = cur ^ 1;
        if (kk + 1 < 8)
            for (int sp = 0; sp < NSPLIT; sp++)
                async16(Ab + (size_t)sp*pstride + (kk+1)*512, la[nxt] + (wave*4 + sp)*512);

        bf16x8 bfr[4];
        for (int t = 0; t < 4; t++)
            bfr[t] = *(const bf16x8*)(w2bf + ((size_t)((oq*4 + t)*8 + kk))*512 + lane*8);

        __builtin_amdgcn_s_setprio(1);
        for (int sp = 0; sp < NSPLIT; sp++) {
            bf16x8 af = *(const bf16x8*)(la[cur] + (wave*4 + sp)*512 + lane*8);
            for (int t = 0; t < 4; t++)
                acc[t] = __builtin_amdgcn_mfma_f32_16x16x32_bf16(af, bfr[t], acc[t], 0, 0, 0);
        }
        __builtin_amdgcn_s_setprio(0);

        // per-wave drain: wave-private LDS regions -> no barrier anywhere.
        asm volatile("s_waitcnt vmcnt(0)" ::: "memory");
    }

    float sinv[4];
    for (int r = 0; r < 4; r++) {
        int n = n0 + wave*16 + quad*4 + r;
        float l = 0.f;
        for (int sp = 0; sp < NSPLIT; sp++)
            l += lpart[(size_t)(sp*BB + b)*NN + n];
        sinv[r] = 1.0f / l;
    }

    for (int t = 0; t < 4; t++) {
        int o = oq*64 + t*16 + lrow;
        int n = n0 + wave*16 + quad*4;
        size_t idx = ((size_t)(b*CC + o))*NN + n;
        float bias = b_proj[o];
        float4 xv = *(const float4*)(x + idx);
        float4 ov;
        ov.x = acc[t][0]*sinv[0] + bias + xv.x;
        ov.y = acc[t][1]*sinv[1] + bias + xv.y;
        ov.z = acc[t][2]*sinv[2] + bias + xv.z;
        ov.w = acc[t][3]*sinv[3] + bias + xv.w;
        *(float4*)(out + idx) = ov;
    }
}

// ---------------------------------------------------------------------------
extern "C" void kernel_launch(void* const* d_in, const int* in_sizes, int n_in,
                              void* d_out, int out_size, void* d_ws, size_t ws_size,
                              hipStream_t stream) {
    const float* x      = (const float*)d_in[0];
    const float* gamma  = (const float*)d_in[1];
    const float* beta   = (const float*)d_in[2];
    const float* w_qkv  = (const float*)d_in[3];
    const float* b_qkv  = (const float*)d_in[4];
    const float* w_proj = (const float*)d_in[5];
    const float* b_proj = (const float*)d_in[6];
    float* out = (float*)d_out;

    const size_t plane = (size_t)BB * NN * CC;     // 4,194,304 elems
    unsigned short* xnT = (unsigned short*)d_ws;
    unsigned short* qsw = xnT + plane;
    unsigned short* ksw = qsw + plane;
    unsigned short* vsw = ksw + plane;
    unsigned short* wbf = vsw + plane;             // 262144 us (chunked)
    unsigned short* opart = wbf + 262144;          // NSPLIT*plane us (bf16)
    float* lpart    = (float*)(opart + (size_t)NSPLIT*plane);  // NSPLIT*BB*NN
    float* partials = lpart + (size_t)NSPLIT*BB*NN;            // 512

    prep_kernel<<<512, 256, 0, stream>>>(x, w_qkv, w_proj, partials, wbf);

    dim3 gnt(64, 4, BB);
    norm_t_kernel<<<gnt, 256, 0, stream>>>(x, gamma, beta, partials, xnT);

    dim3 gq(128, 12);
    qkv_mfma_kernel<<<gq, 256, 0, stream>>>(xnT, wbf, b_qkv, qsw, ksw, vsw);

    attn_mfma_kernel<<<BB*32*NSPLIT, 256, 0, stream>>>(qsw, ksw, vsw, opart, lpart);

    proj_mfma_kernel<<<1024, 256, 0, stream>>>(opart, lpart, wbf + 196608, b_proj, x, out);
}

// Round 12
// 184.602 us; speedup vs baseline: 2.4753x; 1.0168x over previous
//
#include <hip/hip_runtime.h>
#include <math.h>

// Problem constants: x [4, 256, 64, 64] fp32
#define BB   4
#define CC   256
#define NN   4096      // 64*64 spatial
#define GG   8
#define CPG  32        // channels per group
#define EPSV 1e-5f
#define SCALE 0.0625f  // 1/sqrt(256)
#define NSPLIT 4

typedef __attribute__((ext_vector_type(8))) short bf16x8;  // 8 bf16 = 4 VGPRs
typedef __attribute__((ext_vector_type(4))) float f32x4;

struct alignas(8) us4 { unsigned short x, y, z, w; };

static __device__ __forceinline__ unsigned short f2bf(float f) {
    union { float f; unsigned int u; } a; a.f = f;
    unsigned int r = a.u + 0x7fffu + ((a.u >> 16) & 1u);   // RNE
    return (unsigned short)(r >> 16);
}
// async global->LDS, 16B/lane: per-lane gptr, wave-uniform LDS base (+lane*16 by HW)
static __device__ __forceinline__ void async16(const unsigned short* g, unsigned short* l) {
    __builtin_amdgcn_global_load_lds(
        (const __attribute__((address_space(1))) unsigned int*)g,
        (__attribute__((address_space(3))) unsigned int*)l,
        16, 0, 0);
}

// Chunked fragment layout for an R x 256 bf16 matrix:
//   chunk id = (r>>4)*8 + (c>>5); 512 us per chunk;
//   interior  = (((c&31)>>3)*16 + (r&15))*8 + (c&7)   == lane*8 + j for the
//   MFMA fragment. Every fragment is 64 lanes x 16 B contiguous.
//
// K-tile key permutation (R12): within each 32-key attn tile, ksw stores
// sub-tile jg row j' = ORIGINAL key 8*(j'>>2) + 4*jg + (j'&3). Then the
// S^T MFMA output at lane (lrow,quad), slots [jg=0 r0..r3, jg=1 r0..r3]
// is keys [8q..8q+7] -> exactly the PV A-fragment, in order, in-lane.
// V and Q stay in original order (contraction index carries key identity).

// ---------------------------------------------------------------------------
// K0: merged prep: blocks 0..255 = GroupNorm partial stats; 256..511 = weight
// fp32->bf16 conversion into CHUNKED layout.
// ---------------------------------------------------------------------------
__global__ __launch_bounds__(256) void prep_kernel(
    const float* __restrict__ x, const float* __restrict__ w_qkv,
    const float* __restrict__ w_proj, float* __restrict__ partials,
    unsigned short* __restrict__ wbf)
{
    const int tid = threadIdx.x;
    if (blockIdx.x >= 256) {
        int idx = ((blockIdx.x - 256)*256 + tid) * 4;     // 0..262140
        float4 v;
        if (idx < 196608) v = *(const float4*)(w_qkv + idx);
        else              v = *(const float4*)(w_proj + (idx - 196608));
        us4 h = { f2bf(v.x), f2bf(v.y), f2bf(v.z), f2bf(v.w) };
        int o = idx >> 8, c = idx & 255;
        size_t dst = ((size_t)((o >> 4)*8 + (c >> 5)))*512
                   + ((((c & 31) >> 3))*16 + (o & 15))*8 + (c & 7);
        *(us4*)(wbf + dst) = h;
        return;
    }
    const int bg = blockIdx.x >> 3, slice = blockIdx.x & 7;
    const float4* base = (const float4*)(x + (size_t)bg*CPG*NN + slice*16384);
    float s = 0.f, sq = 0.f;
    for (int i = tid; i < 4096; i += 256) {
        float4 v = base[i];
        s  += v.x + v.y + v.z + v.w;
        sq += v.x*v.x + v.y*v.y + v.z*v.z + v.w*v.w;
    }
    __shared__ float ls[256], lq[256];
    ls[tid] = s; lq[tid] = sq;
    __syncthreads();
    for (int off = 128; off > 0; off >>= 1) {
        if (tid < off) { ls[tid] += ls[tid+off]; lq[tid] += lq[tid+off]; }
        __syncthreads();
    }
    if (tid == 0) { partials[blockIdx.x*2] = ls[0]; partials[blockIdx.x*2+1] = lq[0]; }
}

// ---------------------------------------------------------------------------
// K2: normalize + transpose: x [b][c][n] fp32 -> xnT CHUNKED bf16.
// ---------------------------------------------------------------------------
__global__ __launch_bounds__(256) void norm_t_kernel(
    const float* __restrict__ x, const float* __restrict__ gamma,
    const float* __restrict__ beta, const float* __restrict__ partials,
    unsigned short* __restrict__ xnT)
{
    const int n0 = blockIdx.x * 64;
    const int c0 = blockIdx.y * 64;
    const int b  = blockIdx.z;
    const int tid = threadIdx.x;
    __shared__ unsigned short T[64*68];
    __shared__ float ssc[64], ssh[64];
    if (tid < 64) {
        int c = c0 + tid;
        int bg = b*GG + (c >> 5);
        float s = 0.f, sq = 0.f;
        for (int i = 0; i < 8; i++) {
            s  += partials[(bg*8 + i)*2];
            sq += partials[(bg*8 + i)*2 + 1];
        }
        const float cnt = (float)(CPG*NN);
        float mean = s / cnt;
        float var  = sq / cnt - mean*mean;
        float rstd = rsqrtf(var + EPSV);
        float g = gamma[c], be = beta[c];
        ssc[tid] = rstd*g;
        ssh[tid] = be - mean*rstd*g;
    }
    __syncthreads();
    {
        int cl = tid >> 4, n4 = tid & 15;
        for (int i = 0; i < 4; i++) {
            int c = cl + i*16;
            float4 v = *(const float4*)(x + ((size_t)(b*CC + c0 + c))*NN + n0 + n4*4);
            float sc = ssc[c], sh = ssh[c];
            T[(n4*4+0)*68 + c] = f2bf(v.x*sc + sh);
            T[(n4*4+1)*68 + c] = f2bf(v.y*sc + sh);
            T[(n4*4+2)*68 + c] = f2bf(v.z*sc + sh);
            T[(n4*4+3)*68 + c] = f2bf(v.w*sc + sh);
        }
    }
    __syncthreads();
    {
        int nl = tid >> 3, cs = tid & 7;
        for (int i = 0; i < 2; i++) {
            int n = nl + i*32;                       // block-local row
            int gg = (b*NN + n0 + n) >> 4;           // global 16-row group
            int kk = (c0 >> 5) + (cs >> 2);          // 32-col group
            size_t dst = ((size_t)(gg*8 + kk))*512 + ((cs & 3)*16 + (n & 15))*8;
            *(bf16x8*)(xnT + dst) = *(const bf16x8*)&T[n*68 + cs*8];
        }
    }
}

// ---------------------------------------------------------------------------
// K3: QKV MFMA GEMM, R9 staging + R12 K-key permutation in the K epilogue.
// ---------------------------------------------------------------------------
__global__ __launch_bounds__(256, 3) void qkv_mfma_kernel(
    const unsigned short* __restrict__ xnT, const unsigned short* __restrict__ wbf,
    const float* __restrict__ b_qkv,
    unsigned short* __restrict__ qsw, unsigned short* __restrict__ ksw,
    unsigned short* __restrict__ vsw)
{
    const int tid  = threadIdx.x;
    const int wave = tid >> 6, lane = tid & 63;
    const int lrow = lane & 15, quad = lane >> 4;
    const int R0   = blockIdx.x * 128;
    const int b    = blockIdx.x >> 5;
    const int nb0  = (blockIdx.x & 31) * 128;
    const int oBase = blockIdx.y * 64;
    const int which = oBase >> 8;
    const int o0l   = oBase & 255;
    const bool isV  = (which == 2);
    const bool isK  = (which == 1);
    const int wn = wave >> 1, wo = wave & 1;
    const int wg0 = oBase >> 4;                    // weight 16-row group base

    __shared__ unsigned short lw[16384];           // 32 KB: weights (4g x 8kk)
    __shared__ unsigned short lx[2][4096];         // 16 KB: xnT kk-tile dbuf

    // prologue: stage weights (8 chunks/wave) + xnT kk=0 tile (2 chunks/wave)
    const unsigned short* wsrc = wbf + ((size_t)(wg0 + wave))*8*512 + lane*8;
    for (int kk = 0; kk < 8; kk++)
        async16(wsrc + kk*512, lw + (wave*8 + kk)*512);
    const unsigned short* xsrc = xnT + (size_t)R0*CC + lane*8;   // == (R0>>4)*8*512
    for (int i = 0; i < 2; i++) {
        int g = wave*2 + i;
        async16(xsrc + (size_t)g*4096, lx[0] + g*512);
    }
    asm volatile("s_waitcnt vmcnt(0)" ::: "memory");
    __builtin_amdgcn_s_barrier();

    f32x4 acc[4][2];
    for (int s = 0; s < 4; s++) for (int t = 0; t < 2; t++)
        acc[s][t] = (f32x4){0.f, 0.f, 0.f, 0.f};

    for (int kk = 0; kk < 8; kk++) {
        const int cur = kk & 1, nxt = cur ^ 1;
        if (kk + 1 < 8) {
            for (int i = 0; i < 2; i++) {
                int g = wave*2 + i;
                async16(xsrc + (size_t)g*4096 + (kk+1)*512, lx[nxt] + g*512);
            }
        }
        bf16x8 af[4], bfr[2];
        if (!isV) {
            for (int s = 0; s < 4; s++)
                af[s]  = *(const bf16x8*)(lw + (s*8 + kk)*512 + lane*8);
            for (int t = 0; t < 2; t++)
                bfr[t] = *(const bf16x8*)(lx[cur] + (wave*2 + t)*512 + lane*8);
        } else {
            for (int s = 0; s < 4; s++)
                af[s]  = *(const bf16x8*)(lx[cur] + (wn*4 + s)*512 + lane*8);
            for (int t = 0; t < 2; t++)
                bfr[t] = *(const bf16x8*)(lw + ((wo*2 + t)*8 + kk)*512 + lane*8);
        }
        __builtin_amdgcn_s_setprio(1);
        for (int s = 0; s < 4; s++)
            for (int t = 0; t < 2; t++)
                acc[s][t] = __builtin_amdgcn_mfma_f32_16x16x32_bf16(af[s], bfr[t], acc[s][t], 0, 0, 0);
        __builtin_amdgcn_s_setprio(0);
        asm volatile("s_waitcnt vmcnt(0) lgkmcnt(0)" ::: "memory");
        __builtin_amdgcn_s_barrier();
    }

    // epilogue: reuse lw as 8192-us scratch
    unsigned short* lds = lw;

    if (!isV) {
        const float sc = (which == 0) ? SCALE : 1.0f;
        for (int s = 0; s < 4; s++) {
            float bias[4];
            for (int r = 0; r < 4; r++) bias[r] = b_qkv[oBase + s*16 + quad*4 + r];
            for (int t = 0; t < 2; t++) {
                us4 h;
                h.x = f2bf((acc[s][t][0] + bias[0]) * sc);
                h.y = f2bf((acc[s][t][1] + bias[1]) * sc);
                h.z = f2bf((acc[s][t][2] + bias[2]) * sc);
                h.w = f2bf((acc[s][t][3] + bias[3]) * sc);
                int chunk, pos;
                if (!isK) {
                    // Q: original layout (key = t*16 + lrow in order)
                    chunk = (wave*2 + t)*2 + (s>>1);
                    pos = (((s*2 + (quad>>1)) & 3)*16 + lrow)*8 + (quad&1)*4;
                } else {
                    // K: permuted key order. key k = t*16+lrow goes to
                    // sub-tile gp = (lrow>>2)&1, row jp = t*8 + (lrow>>3)*4
                    // + (lrow&3)  ->  S^T output slots become the PV A-frag.
                    int gp = (lrow >> 2) & 1;
                    int jp = t*8 + ((lrow >> 3) << 2) + (lrow & 3);
                    chunk = (wave*2 + gp)*2 + (s>>1);
                    pos = (((s*2 + (quad>>1)) & 3)*16 + jp)*8 + (quad&1)*4;
                }
                *(us4*)&lds[chunk*512 + pos] = h;
            }
        }
    } else {
        for (int s = 0; s < 4; s++)
            for (int t = 0; t < 2; t++) {
                int oc = o0l + wo*32 + t*16 + lrow;
                float bias = b_qkv[512 + oc];
                us4 h;
                h.x = f2bf(acc[s][t][0] + bias);
                h.y = f2bf(acc[s][t][1] + bias);
                h.z = f2bf(acc[s][t][2] + bias);
                h.w = f2bf(acc[s][t][3] + bias);
                int chunk = (wn*2 + (s>>1))*4 + wo*2 + t;
                int pos = (((s&1)*2 + (quad>>1))*16 + lrow)*8 + (quad&1)*4;
                *(us4*)&lds[chunk*512 + pos] = h;
            }
    }
    __syncthreads();

    if (!isV) {
        unsigned short* dst = (which == 0) ? qsw : ksw;
        for (int it = 0; it < 4; it++) {
            int f = it*4 + (tid>>6);
            int ng_l = f >> 1, kk_l = f & 1;
            size_t off = ((size_t)(b*256 + (nb0>>4) + ng_l)*8 + (o0l>>5) + kk_l)*512 + lane*8;
            *(bf16x8*)(dst + off) = *(const bf16x8*)&lds[f*512 + lane*8];
        }
    } else {
        for (int it = 0; it < 4; it++) {
            int f = it*4 + (tid>>6);
            int jg_l = f >> 2, ns_l = f & 3;
            size_t off = ((size_t)(b*128 + (nb0>>5) + jg_l)*16 + (o0l>>4) + ns_l)*512 + lane*8;
            *(bf16x8*)(vsw + off) = *(const bf16x8*)&lds[f*512 + lane*8];
        }
    }
}

// ---------------------------------------------------------------------------
// K4: MFMA flash attention — R11 (XCD swizzle) + R12: NO P LDS round-trip.
// ksw's key permutation makes each lane's 8 exp values exactly its PV
// A-fragment: pack in-register, feed PV directly. Removes 8 P-writes +
// 2 P-reads per wave-iter (~18% of LDS-pipe traffic, the binding resource)
// plus the softmax->lgkm->PV serial chain. LDS 75776 -> 65536 B.
// ---------------------------------------------------------------------------
__global__ __launch_bounds__(256, 2) void attn_mfma_kernel(
    const unsigned short* __restrict__ qsw, const unsigned short* __restrict__ ksw,
    const unsigned short* __restrict__ vsw,
    unsigned short* __restrict__ opart, float* __restrict__ lpart)
{
    const int tid  = threadIdx.x;
    const int wave = tid >> 6, lane = tid & 63;
    const int lrow = lane & 15, quad = lane >> 4;
    const int bx    = blockIdx.x;
    const int sl    = bx & 15;                 // slice id (b*4 + split)
    const int ig    = bx >> 4;                 // 0..31
    const int split = sl & 3;
    const int b     = sl >> 2;
    const int i0w   = ig*128 + wave*32;
    const int koff  = split * (NN / NSPLIT);   // 0,1024,2048,3072
    const int NT    = (NN / NSPLIT) / 32;      // 32 tiles

    __shared__ unsigned short ldsK[2][8192];       // 32 KB: K double buf
    __shared__ unsigned short ldsV[2][8192];       // 32 KB: V double buf

    bf16x8 qf[2][8];
    {
        const unsigned short* qb = qsw + ((size_t)b << 20) + (size_t)i0w*256 + lane*8;
        for (int g = 0; g < 2; g++)
            for (int kk = 0; kk < 8; kk++)
                qf[g][kk] = *(const bf16x8*)(qb + g*4096 + kk*512);
    }

    f32x4 o_acc[2][16];
    for (int g = 0; g < 2; g++)
        for (int ns = 0; ns < 16; ns++)
            o_acc[g][ns] = (f32x4){0.f, 0.f, 0.f, 0.f};
    float lsum[2] = {0.f, 0.f};

    const unsigned short* kp = ksw + ((size_t)b << 20) + (size_t)koff*256 + wave*2048 + lane*8;
    const unsigned short* vp = vsw + ((size_t)b << 20) + (size_t)koff*256 + wave*2048 + lane*8;

    // prologue: stage tile 0 into buffer 0
    for (int t = 0; t < 4; t++) {
        async16(kp + t*512, ldsK[0] + wave*2048 + t*512);
        async16(vp + t*512, ldsV[0] + wave*2048 + t*512);
    }
    asm volatile("s_waitcnt vmcnt(0)" ::: "memory");
    __builtin_amdgcn_s_barrier();

    for (int jt = 0; jt < NT; jt++) {
        const int cur = jt & 1, nxt = cur ^ 1;

        if (jt + 1 < NT) {
            for (int t = 0; t < 4; t++) {
                async16(kp + (size_t)(jt+1)*8192 + t*512, ldsK[nxt] + wave*2048 + t*512);
                async16(vp + (size_t)(jt+1)*8192 + t*512, ldsV[nxt] + wave*2048 + t*512);
            }
        }

        // ---- S^T = K Q^T (keys arrive permuted: slot (jg,quad,r) = key
        // 8*quad + 4*jg + r)
        f32x4 s[2][2];   // [jg key-subtile][g query-group]
        for (int jg = 0; jg < 2; jg++)
            for (int g = 0; g < 2; g++)
                s[jg][g] = (f32x4){0.f, 0.f, 0.f, 0.f};
        const unsigned short* lk = ldsK[cur];
        __builtin_amdgcn_s_setprio(1);
        for (int jg = 0; jg < 2; jg++)
            for (int kk = 0; kk < 8; kk++) {
                bf16x8 kf = *(const bf16x8*)(lk + (jg*8 + kk)*512 + lane*8);
                s[jg][0] = __builtin_amdgcn_mfma_f32_16x16x32_bf16(kf, qf[0][kk], s[jg][0], 0, 0, 0);
                s[jg][1] = __builtin_amdgcn_mfma_f32_16x16x32_bf16(kf, qf[1][kk], s[jg][1], 0, 0, 0);
            }
        __builtin_amdgcn_s_setprio(0);

        // ---- p = exp(s) -> PV A-frags packed entirely in-register.
        // Lane's 8 values = keys 8*quad .. 8*quad+7, in order.
        bf16x8 pa[2];
        for (int g = 0; g < 2; g++) {
            float p0 = __expf(s[0][g][0]);
            float p1 = __expf(s[0][g][1]);
            float p2 = __expf(s[0][g][2]);
            float p3 = __expf(s[0][g][3]);
            float p4 = __expf(s[1][g][0]);
            float p5 = __expf(s[1][g][1]);
            float p6 = __expf(s[1][g][2]);
            float p7 = __expf(s[1][g][3]);
            lsum[g] += p0 + p1 + p2 + p3 + p4 + p5 + p6 + p7;
            union { bf16x8 v; unsigned int w[4]; } u;
            u.w[0] = (unsigned int)f2bf(p0) | ((unsigned int)f2bf(p1) << 16);
            u.w[1] = (unsigned int)f2bf(p2) | ((unsigned int)f2bf(p3) << 16);
            u.w[2] = (unsigned int)f2bf(p4) | ((unsigned int)f2bf(p5) << 16);
            u.w[3] = (unsigned int)f2bf(p6) | ((unsigned int)f2bf(p7) << 16);
            pa[g] = u.v;
        }

        const unsigned short* lv = ldsV[cur];
        __builtin_amdgcn_s_setprio(1);
        for (int ns = 0; ns < 16; ns++) {
            bf16x8 vf = *(const bf16x8*)(lv + ns*512 + lane*8);
            o_acc[0][ns] = __builtin_amdgcn_mfma_f32_16x16x32_bf16(pa[0], vf, o_acc[0][ns], 0, 0, 0);
            o_acc[1][ns] = __builtin_amdgcn_mfma_f32_16x16x32_bf16(pa[1], vf, o_acc[1][ns], 0, 0, 0);
        }
        __builtin_amdgcn_s_setprio(0);

        asm volatile("s_waitcnt vmcnt(0) lgkmcnt(0)" ::: "memory");
        __builtin_amdgcn_s_barrier();
    }

    for (int g = 0; g < 2; g++) {
        float v = lsum[g];
        v += __shfl_xor(v, 16);
        v += __shfl_xor(v, 32);
        lsum[g] = v;
    }

    // epilogue: bounce O through LDS into frag-chunk layout, store b128.
    // (ldsV[0..1] is 16384 contiguous us; each wave uses its 4096-us slice)
    unsigned short* reg = &ldsV[0][0] + wave*4096;
    const size_t planeb = ((size_t)(split*BB + b)) << 20;
    for (int g = 0; g < 2; g++) {
        for (int ns = 0; ns < 16; ns++) {
            int kk = ns >> 1;
            int posbase = ((ns & 1)*2 + (lrow >> 3))*128 + (lrow & 7) + quad*32;
            for (int r = 0; r < 4; r++)
                reg[kk*512 + posbase + r*8] = f2bf(o_acc[g][ns][r]);
        }
        unsigned short* dst = opart + planeb + ((size_t)((i0w >> 4) + g))*4096;
        for (int kk = 0; kk < 8; kk++)
            *(bf16x8*)(dst + kk*512 + lane*8) = *(const bf16x8*)(reg + kk*512 + lane*8);
    }
    if (quad == 0)
        for (int g = 0; g < 2; g++)
            lpart[(size_t)(split*BB + b)*NN + i0w + g*16 + lrow] = lsum[g];
}

// ---------------------------------------------------------------------------
// K5: proj MFMA, R9 structure: async16 staging of opart (wave-private,
// no barriers). Block = 64 n x 64 o, grid 1024, 4 blocks/CU.
// ---------------------------------------------------------------------------
__global__ __launch_bounds__(256, 4) void proj_mfma_kernel(
    const unsigned short* __restrict__ opart, const float* __restrict__ lpart,
    const unsigned short* __restrict__ w2bf, const float* __restrict__ b_proj,
    const float* __restrict__ x, float* __restrict__ out)
{
    const int tid  = threadIdx.x;
    const int wave = tid >> 6, lane = tid & 63;
    const int lrow = lane & 15, quad = lane >> 4;
    const int rt = blockIdx.x & 255;           // row-tile (64 rows)
    const int oq = blockIdx.x >> 8;            // o-quarter (64 outs)
    const int b  = rt >> 6;
    const int n0 = (rt & 63) * 64;

    const int rg = (n0 >> 4) + wave;           // 16-row group within batch
    const unsigned short* Ab = opart + ((size_t)b << 20) + (size_t)rg*4096 + lane*8;
    const size_t pstride = (size_t)BB << 20;   // split-plane stride (us)

    __shared__ unsigned short la[2][8192];     // 32 KB dbuf: 16 chunks (w*4+sp)

    // prologue: stage kk=0 (wave-private: own rg, 4 split planes)
    for (int sp = 0; sp < NSPLIT; sp++)
        async16(Ab + (size_t)sp*pstride, la[0] + (wave*4 + sp)*512);
    asm volatile("s_waitcnt vmcnt(0)" ::: "memory");

    f32x4 acc[4];
    for (int t = 0; t < 4; t++) acc[t] = (f32x4){0.f, 0.f, 0.f, 0.f};

    for (int kk = 0; kk < 8; kk++) {
        const int cur = kk & 1, nxt = cur ^ 1;
        if (kk + 1 < 8)
            for (int sp = 0; sp < NSPLIT; sp++)
                async16(Ab + (size_t)sp*pstride + (kk+1)*512, la[nxt] + (wave*4 + sp)*512);

        bf16x8 bfr[4];
        for (int t = 0; t < 4; t++)
            bfr[t] = *(const bf16x8*)(w2bf + ((size_t)((oq*4 + t)*8 + kk))*512 + lane*8);

        __builtin_amdgcn_s_setprio(1);
        for (int sp = 0; sp < NSPLIT; sp++) {
            bf16x8 af = *(const bf16x8*)(la[cur] + (wave*4 + sp)*512 + lane*8);
            for (int t = 0; t < 4; t++)
                acc[t] = __builtin_amdgcn_mfma_f32_16x16x32_bf16(af, bfr[t], acc[t], 0, 0, 0);
        }
        __builtin_amdgcn_s_setprio(0);

        // per-wave drain: wave-private LDS regions -> no barrier anywhere.
        asm volatile("s_waitcnt vmcnt(0)" ::: "memory");
    }

    float sinv[4];
    for (int r = 0; r < 4; r++) {
        int n = n0 + wave*16 + quad*4 + r;
        float l = 0.f;
        for (int sp = 0; sp < NSPLIT; sp++)
            l += lpart[(size_t)(sp*BB + b)*NN + n];
        sinv[r] = 1.0f / l;
    }

    for (int t = 0; t < 4; t++) {
        int o = oq*64 + t*16 + lrow;
        int n = n0 + wave*16 + quad*4;
        size_t idx = ((size_t)(b*CC + o))*NN + n;
        float bias = b_proj[o];
        float4 xv = *(const float4*)(x + idx);
        float4 ov;
        ov.x = acc[t][0]*sinv[0] + bias + xv.x;
        ov.y = acc[t][1]*sinv[1] + bias + xv.y;
        ov.z = acc[t][2]*sinv[2] + bias + xv.z;
        ov.w = acc[t][3]*sinv[3] + bias + xv.w;
        *(float4*)(out + idx) = ov;
    }
}

// ---------------------------------------------------------------------------
extern "C" void kernel_launch(void* const* d_in, const int* in_sizes, int n_in,
                              void* d_out, int out_size, void* d_ws, size_t ws_size,
                              hipStream_t stream) {
    const float* x      = (const float*)d_in[0];
    const float* gamma  = (const float*)d_in[1];
    const float* beta   = (const float*)d_in[2];
    const float* w_qkv  = (const float*)d_in[3];
    const float* b_qkv  = (const float*)d_in[4];
    const float* w_proj = (const float*)d_in[5];
    const float* b_proj = (const float*)d_in[6];
    float* out = (float*)d_out;

    const size_t plane = (size_t)BB * NN * CC;     // 4,194,304 elems
    unsigned short* xnT = (unsigned short*)d_ws;
    unsigned short* qsw = xnT + plane;
    unsigned short* ksw = qsw + plane;
    unsigned short* vsw = ksw + plane;
    unsigned short* wbf = vsw + plane;             // 262144 us (chunked)
    unsigned short* opart = wbf + 262144;          // NSPLIT*plane us (bf16)
    float* lpart    = (float*)(opart + (size_t)NSPLIT*plane);  // NSPLIT*BB*NN
    float* partials = lpart + (size_t)NSPLIT*BB*NN;            // 512

    prep_kernel<<<512, 256, 0, stream>>>(x, w_qkv, w_proj, partials, wbf);

    dim3 gnt(64, 4, BB);
    norm_t_kernel<<<gnt, 256, 0, stream>>>(x, gamma, beta, partials, xnT);

    dim3 gq(128, 12);
    qkv_mfma_kernel<<<gq, 256, 0, stream>>>(xnT, wbf, b_qkv, qsw, ksw, vsw);

    attn_mfma_kernel<<<BB*32*NSPLIT, 256, 0, stream>>>(qsw, ksw, vsw, opart, lpart);

    proj_mfma_kernel<<<1024, 256, 0, stream>>>(opart, lpart, wbf + 196608, b_proj, x, out);
}